// Round 3
// baseline (5839.267 us; speedup 1.0000x reference)
//
#include <hip/hip_runtime.h>
#include <cmath>

constexpr int SEQ = 64;    // sequence length
constexpr int NB  = 128;   // batch
constexpr int H   = 256;   // hidden
constexpr int DIN = 128;   // composed token dim
constexpr int DE  = 256;   // word emb dim
constexpr int NA  = 64;    // actions
constexpr int S1  = 41;    // STACK_SIZE+1
constexpr int MS  = 100;   // max steps
constexpr int G4  = 1024;  // 4*H
constexpr int HW  = 128;   // hidden units owned per WG (half)

__device__ __forceinline__ float sigf(float x){ return 1.0f/(1.0f+expf(-x)); }

#define AT_ST(p,v) __hip_atomic_store((p),(v),__ATOMIC_RELAXED,__HIP_MEMORY_SCOPE_AGENT)
#define AT_LD(p)   __hip_atomic_load((p),__ATOMIC_RELAXED,__HIP_MEMORY_SCOPE_AGENT)

// ---------------- transpose: in [R][C] -> out [C][R]
__global__ void transpose_k(const float* __restrict__ in, float* __restrict__ out,
                            int R, int C){
  __shared__ float t[32][33];
  int bx = blockIdx.x*32, by = blockIdx.y*32;
  int x = threadIdx.x, y = threadIdx.y;   // block 32x8
  #pragma unroll
  for (int j = 0; j < 32; j += 8)
    t[y+j][x] = in[(size_t)(by+y+j)*C + bx + x];
  __syncthreads();
  #pragma unroll
  for (int j = 0; j < 32; j += 8)
    out[(size_t)(bx+y+j)*R + by + x] = t[x][y+j];
}

// hist_xz[a][r] = hist_Wih[r,:] . action_emb[a,:] + hist_bih[r] + hist_bhh[r]
__global__ void hist_proj_kernel(const float* __restrict__ Wih,
                                 const float* __restrict__ bih,
                                 const float* __restrict__ bhh,
                                 const float* __restrict__ aemb,
                                 float* __restrict__ out){
  int a = blockIdx.x, t = threadIdx.x;
  __shared__ float e[64];
  if (t < 64) e[t] = aemb[a*64 + t];
  __syncthreads();
  for (int r = t; r < G4; r += blockDim.x){
    const float* w = Wih + r*64;
    float acc = bih[r] + bhh[r];
    #pragma unroll
    for (int k = 0; k < 64; k += 4)
      acc += w[k]*e[k] + w[k+1]*e[k+1] + w[k+2]*e[k+2] + w[k+3]*e[k+3];
    out[a*G4 + r] = acc;
  }
}

// Pairwise WG sync: publish my seq, spin (relaxed) for partner, acquire-fence.
__device__ __forceinline__ void pair_sync(int* myflag, int* ptflag, int seq, int tid){
  __syncthreads();   // drain all threads' data stores (vmcnt(0) at barrier)
  if (tid == 0){
    __hip_atomic_store(myflag, seq, __ATOMIC_RELEASE, __HIP_MEMORY_SCOPE_AGENT);
    int it = 0;
    while (__hip_atomic_load(ptflag, __ATOMIC_RELAXED, __HIP_MEMORY_SCOPE_AGENT) < seq){
      if (++it > (1<<24)) break;                 // bailout: avoid infinite hang
      __builtin_amdgcn_s_sleep(2);
    }
    (void)__hip_atomic_load(ptflag, __ATOMIC_ACQUIRE, __HIP_MEMORY_SCOPE_AGENT);
  }
  __syncthreads();
}

// 256 WGs: pair (b, b+128) splits one batch element by hidden units.
// WG w owns units [128w, 128w+128); gate rows {g*256+128w+u} stay local.
__global__ __launch_bounds__(512, 2)
void parser_kernel(const int* __restrict__ tokens,
                   const float* __restrict__ word_emb,
                   const float* __restrict__ Wt_cmp,   // [256][128]
                   const float* __restrict__ compose_b,
                   const float* __restrict__ h0,
                   const float* __restrict__ c0,
                   const float* __restrict__ Wt_pbih,  // [128][1024]
                   const float* __restrict__ Wt_pb,    // [256][1024]
                   const float* __restrict__ pb_bih,
                   const float* __restrict__ pb_bhh,
                   const float* __restrict__ Wt_stih,  // [128][1024]
                   const float* __restrict__ Wt_st,    // [256][1024]
                   const float* __restrict__ st_bih,
                   const float* __restrict__ st_bhh,
                   const float* __restrict__ Wt_hi,    // [256][1024]
                   const float* __restrict__ Wt_sum,   // [768][256]
                   const float* __restrict__ sum_b,
                   const float* __restrict__ Wt_act,   // [256][64]
                   const float* __restrict__ act_b,
                   const int* __restrict__ stack_map,
                   const int* __restrict__ buffer_map,
                   const float* __restrict__ histxz,   // [64][1024]
                   float* __restrict__ pb_zx,   // [B][64][1024]   (own cols only)
                   float* __restrict__ st_zx,   // [B][65][1024]   (own cols only)
                   float* __restrict__ bufh,    // [B][64][256]
                   float* __restrict__ xstate,  // [B][2par][2w][2vec][128]
                   float* __restrict__ xsumm,   // [B][2par][2w][128]
                   int*   __restrict__ xflag,   // [B][2w][64]
                   float* __restrict__ out)     // [100][128][64]
{
  __shared__ __align__(16) float u0[12288];  // P0: tok[64][128]+emb[16][256]; P1: pc[128]; main: sh[41][128]+sc[41][128]
  __shared__ __align__(16) float u1[2048];   // partials (f64 summary/logits) | z slices
  __shared__ __align__(16) float xfull[768]; // [stack_top | bstate | ah] (also P1 h_full in [0:256))
  __shared__ __align__(16) float summf[H];
  __shared__ __align__(16) float lgf[NA];
  __shared__ __align__(16) float ahw[HW];
  __shared__ __align__(16) float acw[HW];
  __shared__ __align__(16) float h0l[H];
  __shared__ __align__(16) float c0h[HW];
  __shared__ int ctl[16];

  const int bid = blockIdx.x;
  const int b   = bid & 127;
  const int w   = bid >> 7, pw = 1 - w;
  const int tid = threadIdx.x;

  int* myflag = xflag + (size_t)(b*2 + w )*64;
  int* ptflag = xflag + (size_t)(b*2 + pw)*64;
  int seq = 0;

  float* tokl   = u0;              // [64][128]
  float* embs   = u0 + SEQ*DIN;    // [16][256]
  float* stackh = u0;              // [41][128] slice
  float* stackc = u0 + S1*HW;      // [41][128] slice

  if (tid < H)  h0l[tid] = h0[tid];
  if (tid < HW) c0h[tid] = c0[128*w + tid];
  __syncthreads();

  // ---------------- P0a (replicated): tok[t] = relu(W_c @ emb[tokens[t,b]] + b_c)
  {
    const int d = tid & 127, tb = tid >> 7;
    const float cb = compose_b[d];
    for (int pass = 0; pass < 4; ++pass){
      for (int j = tid >> 8; j < 16; j += 2){
        int tt = pass*16 + j;
        int id = tokens[tt*NB + b];
        embs[j*DE + (tid & 255)] = word_emb[(size_t)id*DE + (tid & 255)];
      }
      __syncthreads();
      float a0 = 0.f, a1 = 0.f, a2 = 0.f, a3 = 0.f;
      const float* eb = embs + (tb*4)*DE;
      for (int c = 0; c < DE; ++c){
        float wv = Wt_cmp[c*DIN + d];
        a0 += wv*eb[c]; a1 += wv*eb[DE + c]; a2 += wv*eb[2*DE + c]; a3 += wv*eb[3*DE + c];
      }
      int t0 = pass*16 + tb*4;
      tokl[(t0    )*DIN + d] = fmaxf(a0 + cb, 0.f);
      tokl[(t0 + 1)*DIN + d] = fmaxf(a1 + cb, 0.f);
      tokl[(t0 + 2)*DIN + d] = fmaxf(a2 + cb, 0.f);
      tokl[(t0 + 3)*DIN + d] = fmaxf(a3 + cb, 0.f);
      __syncthreads();
    }
  }

  // ---------------- P0b (halved): zx = Wih @ tok + (bih+bhh) for OWN cols only
  {
    const int m  = tid >> 8;                 // 0: pb, 1: st
    const int i2 = tid & 255;
    const int g  = i2 >> 6, lu2 = 2*(i2 & 63);
    const int col = g*256 + 128*w + lu2;
    const float* Wt = m ? Wt_stih : Wt_pbih;
    float* zxb = m ? (st_zx + (size_t)b*(SEQ+1)*G4) : (pb_zx + (size_t)b*SEQ*G4);
    const float* bA = m ? st_bih : pb_bih;
    const float* bB = m ? st_bhh : pb_bhh;
    const float b0 = bA[col] + bB[col], b1 = bA[col+1] + bB[col+1];
    for (int blk = 0; blk < 4; ++blk){
      float a0[16], a1[16];
      #pragma unroll
      for (int t = 0; t < 16; ++t){ a0[t] = 0.f; a1[t] = 0.f; }
      const float* tb = tokl + (blk*16)*DIN;
      for (int c = 0; c < DIN; ++c){
        float2 wv = *(const float2*)(Wt + (size_t)c*G4 + col);
        #pragma unroll
        for (int t = 0; t < 16; ++t){
          float x = tb[t*DIN + c];
          a0[t] += wv.x*x; a1[t] += wv.y*x;
        }
      }
      #pragma unroll
      for (int t = 0; t < 16; ++t)
        *(float2*)(zxb + (size_t)(blk*16 + t)*G4 + col) = make_float2(a0[t]+b0, a1[t]+b1);
    }
    if (m) *(float2*)(zxb + (size_t)SEQ*G4 + col) = make_float2(b0, b1);
  }
  __syncthreads();

  // ---------------- P1: pre-buffer LSTM (row-split, pairwise h exchange)
  if (tid < H)  xfull[tid] = h0l[tid];   // h_full
  if (tid < HW) u0[tid] = c0h[tid];      // own c slice (tokl dead now)
  __syncthreads();
  for (int k = 0; k < SEQ; ++k){
    const int tt = SEQ - 1 - k;
    {
      const int ch = tid >> 8, i2 = tid & 255;
      const int g = i2 >> 6, lu2 = 2*(i2 & 63);
      const int col = g*256 + 128*w + lu2;
      const int scx = g*128 + lu2;
      float a0 = 0.f, a1 = 0.f;
      for (int c = ch*128; c < ch*128 + 128; ++c){
        float2 wv = *(const float2*)(Wt_pb + (size_t)c*G4 + col);
        float x = xfull[c];
        a0 += wv.x*x; a1 += wv.y*x;
      }
      if (ch == 0){
        float2 zx = *(const float2*)(pb_zx + ((size_t)b*SEQ + tt)*G4 + col);
        a0 += zx.x; a1 += zx.y;
      }
      u1[ch*512 + scx] = a0; u1[ch*512 + scx + 1] = a1;
    }
    __syncthreads();
    if (tid < HW){
      const int lu = tid;
      float zi = u1[       lu] + u1[512 +        lu];
      float zf = u1[128 +  lu] + u1[512 + 128 +  lu];
      float zg = u1[256 +  lu] + u1[512 + 256 +  lu];
      float zo = u1[384 +  lu] + u1[512 + 384 +  lu];
      float c2 = sigf(zf)*u0[lu] + sigf(zi)*tanhf(zg);
      float h2 = sigf(zo)*tanhf(c2);
      u0[lu] = c2;
      xfull[128*w + lu] = h2;
      AT_ST(&bufh[((size_t)b*SEQ + k)*H + 128*w + lu], h2);
      AT_ST(&xstate[(((size_t)(b*2 + (k&1))*2 + w)*2 + 0)*HW + lu], h2);
    }
    ++seq;
    pair_sync(myflag, ptflag, seq, tid);
    if (tid < HW)
      xfull[128*pw + tid] = AT_LD(&xstate[(((size_t)(b*2 + (k&1))*2 + pw)*2 + 0)*HW + tid]);
    __syncthreads();
  }

  // ---------------- main init
  // bstate := final buf h (currently xfull[0:256)); then stack_top/ah := h0
  if (tid < H) xfull[256 + tid] = xfull[tid];
  __syncthreads();
  if (tid < H){ xfull[tid] = h0l[tid]; xfull[512 + tid] = h0l[tid]; }
  for (int i = tid; i < 2*S1*HW; i += 512) u0[i] = 0.f;
  __syncthreads();
  if (tid < HW){
    stackh[tid] = h0l[128*w + tid];
    stackc[tid] = c0h[tid];
    ahw[tid] = h0l[128*w + tid];
    acw[tid] = c0h[tid];
  }
  if (tid == 0){ ctl[0] = 0; ctl[1] = SEQ; ctl[2] = SEQ - 1; }
  __syncthreads();

  // ---------------- main parser loop
  for (int step = 0; step < MS; ++step){
    const int spos = ctl[0], bposc = ctl[1], sinc = ctl[2];
    const int par = step & 1;

    // A: summary partial rows (own 128), f64, 8-way c-split of 768
    {
      const int cg = tid >> 6, i2 = tid & 63;
      const int lu2 = 2*i2, col = 128*w + lu2;
      double d0 = 0.0, d1 = 0.0;
      for (int c = cg*96; c < cg*96 + 96; ++c){
        float2 wv = *(const float2*)(Wt_sum + (size_t)c*H + col);
        double x = (double)xfull[c];
        d0 += (double)wv.x*x; d1 += (double)wv.y*x;
      }
      double* pd = (double*)u1;
      pd[cg*128 + lu2] = d0; pd[cg*128 + lu2 + 1] = d1;
    }
    __syncthreads();
    if (tid < HW){
      const double* pd = (const double*)u1;
      double s = (double)sum_b[128*w + tid];
      #pragma unroll
      for (int gq = 0; gq < 8; ++gq) s += pd[gq*128 + tid];
      float sv = fmaxf((float)s, 0.f);
      summf[128*w + tid] = sv;
      AT_ST(&xsumm[((size_t)(b*2 + par)*2 + w)*HW + tid], sv);
    }
    ++seq;
    pair_sync(myflag, ptflag, seq, tid);
    if (tid < HW)
      summf[128*pw + tid] = AT_LD(&xsumm[((size_t)(b*2 + par)*2 + pw)*HW + tid]);
    __syncthreads();

    // B: logits — BOTH WGs compute all 64 (identical bits), f64, 8-way c-split
    {
      const int col = tid & 63, cg = tid >> 6;
      double d0 = 0.0;
      for (int c = cg*32; c < cg*32 + 32; ++c)
        d0 += (double)Wt_act[(size_t)c*NA + col] * (double)summf[c];
      double* pd = (double*)u1;
      pd[cg*64 + col] = d0;
    }
    __syncthreads();
    if (tid < NA){
      const double* pd = (const double*)u1;
      double s = (double)act_b[tid];
      #pragma unroll
      for (int gq = 0; gq < 8; ++gq) s += pd[gq*64 + tid];
      lgf[tid] = (float)s;
    }
    __syncthreads();

    // C: softmax + out (own 32 cols) + argmax + control (replicated)
    if (tid < NA){
      float v = lgf[tid];
      float mx = v;
      #pragma unroll
      for (int o = 32; o > 0; o >>= 1) mx = fmaxf(mx, __shfl_xor(mx, o));
      float ex = expf(v - mx), sm = ex;
      #pragma unroll
      for (int o = 32; o > 0; o >>= 1) sm += __shfl_xor(sm, o);
      float lsm = v - mx - logf(sm);
      if (tid >= 32*w && tid < 32*w + 32)
        out[(((size_t)step*NB) + b)*NA + tid] = lsm;
      float bv = v; int bi = tid;
      #pragma unroll
      for (int o = 32; o > 0; o >>= 1){
        float ov = __shfl_xor(bv, o); int oi = __shfl_xor(bi, o);
        if (ov > bv || (ov == bv && oi < bi)){ bv = ov; bi = oi; }
      }
      if (tid == 0){
        int a = bi;
        int sop = stack_map[a], bop = buffer_map[a];
        if (spos == 0 && sop == -1) sop = 0;
        if (spos >= S1 - 1 && sop == 1) sop = 0;
        if (bposc == 0 && bop == -1) bop = 0;
        int push  = (sop == 1) ? 1 : 0;
        int widx  = (spos + 1 < S1 - 1) ? spos + 1 : S1 - 1;
        int sposn = spos + sop;
        int bposn = bposc + bop;
        int ne    = (bposn > 0) ? 1 : 0;
        int gidx  = bposn - 1; if (gidx < 0) gidx = 0; if (gidx > SEQ - 1) gidx = SEQ - 1;
        ctl[3] = a; ctl[4] = push; ctl[5] = widx; ctl[6] = sposn;
        ctl[7] = bposn; ctl[8] = ne; ctl[9] = gidx;
      }
    }
    __syncthreads();

    // D: z slices — threads<256: st (x = stack_top); >=256: hist (x = ah)
    {
      const int ai = ctl[3];
      const int half = tid >> 8, i2 = tid & 255;
      const int g = i2 >> 6, lu2 = 2*(i2 & 63);
      const int col = g*256 + 128*w + lu2;
      const int scx = g*128 + lu2;
      const float* Wt = half ? Wt_hi : Wt_st;
      const float* xv = half ? (xfull + 512) : xfull;
      float a0 = 0.f, a1 = 0.f;
      for (int c = 0; c < H; ++c){
        float2 wv = *(const float2*)(Wt + (size_t)c*G4 + col);
        float x = xv[c];
        a0 += wv.x*x; a1 += wv.y*x;
      }
      float2 ad = half ? *(const float2*)(histxz + (size_t)ai*G4 + col)
                       : *(const float2*)(st_zx + ((size_t)b*(SEQ+1) + sinc)*G4 + col);
      u1[half*512 + scx] = a0 + ad.x;
      u1[half*512 + scx + 1] = a1 + ad.y;
    }
    __syncthreads();

    // E: gates + state commit (own units)
    {
      const int push = ctl[4], widx = ctl[5];
      if (tid < HW){
        const int lu = tid;
        float zi = u1[lu], zf = u1[128+lu], zg = u1[256+lu], zo = u1[384+lu];
        float cold = stackc[spos*HW + lu];
        float c2 = sigf(zf)*cold + sigf(zi)*tanhf(zg);
        float h2 = sigf(zo)*tanhf(c2);
        if (push){ stackh[widx*HW + lu] = h2; stackc[widx*HW + lu] = c2; }
      } else if (tid < 2*HW){
        const int lu = tid - HW;
        float zi = u1[512+lu], zf = u1[512+128+lu], zg = u1[512+256+lu], zo = u1[512+384+lu];
        float c2 = sigf(zf)*acw[lu] + sigf(zi)*tanhf(zg);
        float h2 = sigf(zo)*tanhf(c2);
        acw[lu] = c2; ahw[lu] = h2;
      }
      if (tid == 0){ ctl[0] = ctl[6]; ctl[1] = ctl[7]; ctl[2] = ctl[8] ? ctl[9] : SEQ; }
    }
    __syncthreads();

    // F: publish new state halves; assemble next x_full
    {
      const int sposn = ctl[6], ne = ctl[8], gidx = ctl[9];
      if (tid < HW){
        float sth = stackh[sposn*HW + tid];
        float ahv = ahw[tid];
        xfull[128*w + tid] = sth;
        xfull[512 + 128*w + tid] = ahv;
        AT_ST(&xstate[(((size_t)(b*2 + par)*2 + w)*2 + 0)*HW + tid], sth);
        AT_ST(&xstate[(((size_t)(b*2 + par)*2 + w)*2 + 1)*HW + tid], ahv);
      } else if (tid >= 256){
        int j = tid - 256;
        xfull[256 + j] = ne ? bufh[((size_t)b*SEQ + gidx)*H + j] : h0l[j];
      }
      ++seq;
      pair_sync(myflag, ptflag, seq, tid);
      if (tid < HW){
        xfull[128*pw + tid]       = AT_LD(&xstate[(((size_t)(b*2 + par)*2 + pw)*2 + 0)*HW + tid]);
        xfull[512 + 128*pw + tid] = AT_LD(&xstate[(((size_t)(b*2 + par)*2 + pw)*2 + 1)*HW + tid]);
      }
      __syncthreads();
    }
  }
}

extern "C" void kernel_launch(void* const* d_in, const int* in_sizes, int n_in,
                              void* d_out, int out_size, void* d_ws, size_t ws_size,
                              hipStream_t stream){
  (void)in_sizes; (void)n_in; (void)out_size; (void)ws_size;
  const int*   tokens    = (const int*)  d_in[0];
  const float* word_emb  = (const float*)d_in[1];
  const float* compose_W = (const float*)d_in[2];
  const float* compose_b = (const float*)d_in[3];
  const float* h0        = (const float*)d_in[4];
  const float* c0        = (const float*)d_in[5];
  const float* pb_Wih    = (const float*)d_in[6];
  const float* pb_Whh    = (const float*)d_in[7];
  const float* pb_bih    = (const float*)d_in[8];
  const float* pb_bhh    = (const float*)d_in[9];
  const float* st_Wih    = (const float*)d_in[10];
  const float* st_Whh    = (const float*)d_in[11];
  const float* st_bih    = (const float*)d_in[12];
  const float* st_bhh    = (const float*)d_in[13];
  const float* hist_Wih  = (const float*)d_in[14];
  const float* hist_Whh  = (const float*)d_in[15];
  const float* hist_bih  = (const float*)d_in[16];
  const float* hist_bhh  = (const float*)d_in[17];
  const float* sum_W     = (const float*)d_in[18];
  const float* sum_b     = (const float*)d_in[19];
  const float* act_W     = (const float*)d_in[20];
  const float* act_b     = (const float*)d_in[21];
  const float* action_emb= (const float*)d_in[22];
  const int*   stack_map = (const int*)  d_in[23];
  const int*   buffer_map= (const int*)  d_in[24];

  float* ws     = (float*)d_ws;
  float* pb_zx  = ws;                                  // 128*64*1024
  float* st_zx  = pb_zx + (size_t)NB*SEQ*G4;           // 128*65*1024
  float* bufh   = st_zx + (size_t)NB*(SEQ+1)*G4;       // 128*64*256
  float* histxz = bufh  + (size_t)NB*SEQ*H;            // 64*1024
  float* Wt_pb  = histxz + (size_t)NA*G4;              // [256][1024]
  float* Wt_st  = Wt_pb  + (size_t)H*G4;
  float* Wt_hi  = Wt_st  + (size_t)H*G4;
  float* Wt_sum = Wt_hi  + (size_t)H*G4;               // [768][256]
  float* Wt_act = Wt_sum + (size_t)768*H;              // [256][64]
  float* Wt_pbih= Wt_act + (size_t)H*NA;               // [128][1024]
  float* Wt_stih= Wt_pbih+ (size_t)DIN*G4;             // [128][1024]
  float* Wt_cmp = Wt_stih+ (size_t)DIN*G4;             // [256][128]
  float* xstate = Wt_cmp + (size_t)DE*DIN;             // 128*2*2*2*128
  float* xsumm  = xstate + (size_t)NB*2*2*2*HW;        // 128*2*2*128
  int*   xflag  = (int*)(xsumm + (size_t)NB*2*2*HW);   // 128*2*64 ints

  dim3 blk(32, 8);
  transpose_k<<<dim3(256/32, 1024/32), blk, 0, stream>>>(pb_Whh,   Wt_pb,  1024, 256);
  transpose_k<<<dim3(256/32, 1024/32), blk, 0, stream>>>(st_Whh,   Wt_st,  1024, 256);
  transpose_k<<<dim3(256/32, 1024/32), blk, 0, stream>>>(hist_Whh, Wt_hi,  1024, 256);
  transpose_k<<<dim3(768/32,  256/32), blk, 0, stream>>>(sum_W,    Wt_sum,  256, 768);
  transpose_k<<<dim3(256/32,   64/32), blk, 0, stream>>>(act_W,    Wt_act,   64, 256);
  transpose_k<<<dim3(128/32, 1024/32), blk, 0, stream>>>(pb_Wih,   Wt_pbih,1024, 128);
  transpose_k<<<dim3(128/32, 1024/32), blk, 0, stream>>>(st_Wih,   Wt_stih,1024, 128);
  transpose_k<<<dim3(256/32,  128/32), blk, 0, stream>>>(compose_W,Wt_cmp,  128, 256);
  hist_proj_kernel<<<dim3(NA), dim3(256), 0, stream>>>(hist_Wih, hist_bih, hist_bhh,
                                                       action_emb, histxz);

  parser_kernel<<<dim3(2*NB), dim3(512), 0, stream>>>(tokens, word_emb, Wt_cmp, compose_b,
      h0, c0, Wt_pbih, Wt_pb, pb_bih, pb_bhh, Wt_stih, Wt_st, st_bih, st_bhh,
      Wt_hi, Wt_sum, sum_b, Wt_act, act_b, stack_map, buffer_map,
      histxz, pb_zx, st_zx, bufh, xstate, xsumm, xflag, (float*)d_out);
}

// Round 4
// 5245.766 us; speedup vs baseline: 1.1131x; 1.1131x over previous
//
#include <hip/hip_runtime.h>
#include <cmath>

constexpr int SEQ = 64;    // sequence length
constexpr int NB  = 128;   // batch
constexpr int H   = 256;   // hidden
constexpr int DIN = 128;   // composed token dim
constexpr int DE  = 256;   // word emb dim
constexpr int NA  = 64;    // actions
constexpr int S1  = 41;    // STACK_SIZE+1
constexpr int MS  = 100;   // max steps
constexpr int G4  = 1024;  // 4*H

__device__ __forceinline__ float sigf(float x){ return 1.0f/(1.0f+expf(-x)); }

// ---------------- transpose: in [R][C] -> out [C][R]
__global__ void transpose_k(const float* __restrict__ in, float* __restrict__ out,
                            int R, int C){
  __shared__ float t[32][33];
  int bx = blockIdx.x*32, by = blockIdx.y*32;
  int x = threadIdx.x, y = threadIdx.y;   // block 32x8
  #pragma unroll
  for (int j = 0; j < 32; j += 8)
    t[y+j][x] = in[(size_t)(by+y+j)*C + bx + x];
  __syncthreads();
  #pragma unroll
  for (int j = 0; j < 32; j += 8)
    out[(size_t)(bx+y+j)*R + by + x] = t[x][y+j];
}

// hist_xz[a][r] = hist_Wih[r,:] . action_emb[a,:] + hist_bih[r] + hist_bhh[r]
__global__ void hist_proj_kernel(const float* __restrict__ Wih,
                                 const float* __restrict__ bih,
                                 const float* __restrict__ bhh,
                                 const float* __restrict__ aemb,
                                 float* __restrict__ out){
  int a = blockIdx.x, t = threadIdx.x;
  __shared__ float e[64];
  if (t < 64) e[t] = aemb[a*64 + t];
  __syncthreads();
  for (int r = t; r < G4; r += blockDim.x){
    const float* w = Wih + r*64;
    float acc = bih[r] + bhh[r];
    #pragma unroll
    for (int k = 0; k < 64; k += 4)
      acc += w[k]*e[k] + w[k+1]*e[k+1] + w[k+2]*e[k+2] + w[k+3]*e[k+3];
    out[a*G4 + r] = acc;
  }
}

// One workgroup (1024 threads) per batch element. All three big matvecs
// (summary / st_Whh / hist_Whh) are action-independent -> computed in ONE
// merged barrier-free stream phase; the action enters only via histxz[a]
// and the commit decisions.
__global__ __launch_bounds__(1024, 4)
void parser_kernel(const int* __restrict__ tokens,
                   const float* __restrict__ word_emb,
                   const float* __restrict__ Wt_cmp,   // [256][128]
                   const float* __restrict__ compose_b,
                   const float* __restrict__ h0,
                   const float* __restrict__ c0,
                   const float* __restrict__ Wt_pbih,  // [128][1024]
                   const float* __restrict__ Wt_pb,    // [256][1024]
                   const float* __restrict__ pb_bih,
                   const float* __restrict__ pb_bhh,
                   const float* __restrict__ Wt_stih,  // [128][1024]
                   const float* __restrict__ Wt_st,    // [256][1024]
                   const float* __restrict__ st_bih,
                   const float* __restrict__ st_bhh,
                   const float* __restrict__ Wt_hi,    // [256][1024]
                   const float* __restrict__ Wt_sum,   // [768][256]
                   const float* __restrict__ sum_b,
                   const float* __restrict__ Wt_act,   // [256][64]
                   const float* __restrict__ act_b,
                   const int* __restrict__ stack_map,
                   const int* __restrict__ buffer_map,
                   const float* __restrict__ histxz,   // [64][1024]
                   float* __restrict__ pb_zx,   // [B][64][1024]
                   float* __restrict__ st_zx,   // [B][65][1024] (row 64 = bias only)
                   float* __restrict__ bufh,    // [B][64][256]
                   float* __restrict__ scst,    // [B][41][256] stack c in global
                   float* __restrict__ out)     // [100][128][64]
{
  // LDS: u0 10496f (P0: tok[64][128]+embs[8][256]; main: stackh[41][256])
  //      u1 3072f  (main: z_st[1024]+z_hi[1024] @0, f64 partials @2048;
  //                 P1: partials[2][1024])
  __shared__ __align__(16) float u0[10496];
  __shared__ __align__(16) float u1[3072];
  __shared__ __align__(16) float summf[H];
  __shared__ __align__(16) float bstate[H];
  __shared__ __align__(16) float ahl[H];
  __shared__ __align__(16) float acl[H];
  __shared__ int ctl[16];

  const int b   = blockIdx.x;
  const int tid = threadIdx.x;

  float* tokl   = u0;              // [64][128]
  float* embs   = u0 + SEQ*DIN;    // [8][256]
  float* stackh = u0;              // [41][256]

  // ---------------- P0a: tok[t] = relu(W_c @ emb[tokens[t,b]] + b_c)
  {
    const int d = tid & 127, tb = tid >> 7;        // tb in 0..7: one token each
    const float cb = compose_b[d];
    for (int pass = 0; pass < 8; ++pass){
      {
        int j = tid >> 8, l = tid & 255;           // stage rows j, j+4
        int t0 = pass*8 + j, t1 = pass*8 + j + 4;
        embs[j*DE + l]       = word_emb[(size_t)tokens[t0*NB + b]*DE + l];
        embs[(j+4)*DE + l]   = word_emb[(size_t)tokens[t1*NB + b]*DE + l];
      }
      __syncthreads();
      float acc = 0.f;
      const float* eb = embs + tb*DE;
      for (int c = 0; c < DE; ++c)
        acc += Wt_cmp[c*DIN + d] * eb[c];
      tokl[(pass*8 + tb)*DIN + d] = fmaxf(acc + cb, 0.f);
      __syncthreads();
    }
  }

  // ---------------- P0b: zx = Wih @ tok + (bih+bhh); 512 threads per matrix
  {
    const int m  = tid >> 9;                 // 0: pb, 1: st
    const int i  = tid & 511;
    const int col2 = 2*i;
    const float* Wt = m ? Wt_stih : Wt_pbih;
    float* zxb = m ? (st_zx + (size_t)b*(SEQ+1)*G4) : (pb_zx + (size_t)b*SEQ*G4);
    const float* bA = m ? st_bih : pb_bih;
    const float* bB = m ? st_bhh : pb_bhh;
    const float b0 = bA[col2] + bB[col2], b1 = bA[col2+1] + bB[col2+1];
    for (int blk = 0; blk < 4; ++blk){
      float a0[16], a1[16];
      #pragma unroll
      for (int t = 0; t < 16; ++t){ a0[t] = 0.f; a1[t] = 0.f; }
      const float* tb = tokl + (blk*16)*DIN;
      for (int c = 0; c < DIN; ++c){
        float2 wv = *(const float2*)(Wt + (size_t)c*G4 + col2);
        #pragma unroll
        for (int t = 0; t < 16; ++t){
          float x = tb[t*DIN + c];
          a0[t] += wv.x*x; a1[t] += wv.y*x;
        }
      }
      #pragma unroll
      for (int t = 0; t < 16; ++t)
        *(float2*)(zxb + (size_t)(blk*16 + t)*G4 + col2) = make_float2(a0[t]+b0, a1[t]+b1);
    }
    if (m) *(float2*)(zxb + (size_t)SEQ*G4 + col2) = make_float2(b0, b1);
  }
  __syncthreads();

  // ---------------- P1: pre-buffer LSTM over reversed tokens
  // ahl = h (full), register cpb = c (threads 0..255 own unit tid).
  float cpb = 0.f;
  if (tid < H){ ahl[tid] = h0[tid]; cpb = c0[tid]; }
  __syncthreads();
  for (int k = 0; k < SEQ; ++k){
    const int tt = SEQ - 1 - k;
    {
      const int ch = tid >> 9, i = tid & 511, col2 = 2*i;
      float a0 = 0.f, a1 = 0.f;
      for (int c = ch*128; c < ch*128 + 128; ++c){
        float2 wv = *(const float2*)(Wt_pb + (size_t)c*G4 + col2);
        float x = ahl[c];
        a0 += wv.x*x; a1 += wv.y*x;
      }
      if (ch == 0){
        float2 zx = *(const float2*)(pb_zx + ((size_t)b*SEQ + tt)*G4 + col2);
        a0 += zx.x; a1 += zx.y;
      }
      u1[ch*1024 + col2] = a0; u1[ch*1024 + col2 + 1] = a1;
    }
    __syncthreads();
    if (tid < H){
      float zi = u1[tid]       + u1[1024 + tid];
      float zf = u1[256 + tid] + u1[1024 + 256 + tid];
      float zg = u1[512 + tid] + u1[1024 + 512 + tid];
      float zo = u1[768 + tid] + u1[1024 + 768 + tid];
      float c2 = sigf(zf)*cpb + sigf(zi)*tanhf(zg);
      float h2 = sigf(zo)*tanhf(c2);
      cpb = c2;
      ahl[tid] = h2;
      bufh[((size_t)b*SEQ + k)*H + tid] = h2;
    }
    __syncthreads();
  }

  // ---------------- main init
  if (tid < H) bstate[tid] = ahl[tid];          // b_state = buf_h[63]
  __syncthreads();
  for (int i = tid; i < S1*H; i += 1024) stackh[i] = (i < H) ? h0[i] : 0.f;
  {
    float* cst = scst + (size_t)b*S1*H;
    for (int i = tid; i < S1*H; i += 1024) cst[i] = (i < H) ? c0[i] : 0.f;
  }
  if (tid < H){ ahl[tid] = h0[tid]; acl[tid] = c0[tid]; }   // hist LSTM state
  if (tid == 0){ ctl[0] = 0; ctl[1] = SEQ; ctl[2] = SEQ - 1; } // spos, bpos, sin
  __syncthreads();

  // ---------------- main parser loop
  for (int step = 0; step < MS; ++step){
    const int spos = ctl[0], bposc = ctl[1], sinc = ctl[2];

    // PHASE 1 (merged stream, no internal barrier):
    //  t in [0,256):    z_st[4t..4t+3]  = st_Whh @ stack_top + st_zx[sinc]
    //  t in [256,512):  z_hiW[4u..4u+3] = hist_Whh @ ah      (histxz added later)
    //  t in [512,1024): summary f64 partials, 2-way c-split (384 each)
    if (tid < 512){
      const int grp = tid >> 8, lt = tid & 255, col4 = 4*lt;
      const float* Wt = grp ? Wt_hi : Wt_st;
      const float* xv = grp ? ahl : (stackh + spos*H);
      float a0 = 0.f, a1 = 0.f, a2 = 0.f, a3 = 0.f;
      for (int c = 0; c < H; ++c){
        float4 w = *(const float4*)(Wt + (size_t)c*G4 + col4);
        float x = xv[c];
        a0 += w.x*x; a1 += w.y*x; a2 += w.z*x; a3 += w.w*x;
      }
      if (grp == 0){
        float4 ad = *(const float4*)(st_zx + ((size_t)b*(SEQ+1) + sinc)*G4 + col4);
        a0 += ad.x; a1 += ad.y; a2 += ad.z; a3 += ad.w;
      }
      *(float4*)(u1 + grp*1024 + col4) = make_float4(a0, a1, a2, a3);
    } else {
      const int i2 = tid - 512;
      const int col = i2 & 255, cg = i2 >> 8;    // cg in {0,1}
      double acc = 0.0;
      for (int c = cg*384; c < cg*384 + 384; ++c){
        float xc = (c < 256) ? stackh[spos*H + c]
                 : (c < 512) ? bstate[c - 256] : ahl[c - 512];
        acc += (double)Wt_sum[(size_t)c*H + col] * (double)xc;
      }
      ((double*)(u1 + 2048))[cg*256 + col] = acc;
    }
    __syncthreads();

    // PHASE 2: summary reduce + relu
    if (tid < H){
      const double* pd = (const double*)(u1 + 2048);
      summf[tid] = fmaxf((float)(pd[tid] + pd[256 + tid] + (double)sum_b[tid]), 0.f);
    }
    __syncthreads();

    // PHASE 3: logits f64 partials (8-way c-split of 256)
    if (tid < 512){
      const int col = tid & 63, cg = tid >> 6;
      double acc = 0.0;
      for (int c = cg*32; c < cg*32 + 32; ++c)
        acc += (double)Wt_act[(size_t)c*NA + col] * (double)summf[c];
      ((double*)(u1 + 2048))[cg*64 + col] = acc;
    }
    __syncthreads();

    // PHASE 4: wave 0 — logits reduce, log_softmax, store, argmax, control
    if (tid < NA){
      const double* pd = (const double*)(u1 + 2048);
      double s = (double)act_b[tid];
      #pragma unroll
      for (int q = 0; q < 8; ++q) s += pd[q*64 + tid];
      float v = (float)s;
      float mx = v;
      #pragma unroll
      for (int o = 32; o > 0; o >>= 1) mx = fmaxf(mx, __shfl_xor(mx, o));
      float ex = expf(v - mx), sm = ex;
      #pragma unroll
      for (int o = 32; o > 0; o >>= 1) sm += __shfl_xor(sm, o);
      out[(((size_t)step*NB) + b)*NA + tid] = v - mx - logf(sm);
      float bv = v; int bi = tid;     // argmax, first index wins
      #pragma unroll
      for (int o = 32; o > 0; o >>= 1){
        float ov = __shfl_xor(bv, o); int oi = __shfl_xor(bi, o);
        if (ov > bv || (ov == bv && oi < bi)){ bv = ov; bi = oi; }
      }
      if (tid == 0){
        int a = bi;
        int sop = stack_map[a], bop = buffer_map[a];
        if (spos == 0 && sop == -1) sop = 0;
        if (spos >= S1 - 1 && sop == 1) sop = 0;
        if (bposc == 0 && bop == -1) bop = 0;
        int push  = (sop == 1) ? 1 : 0;
        int widx  = (spos + 1 < S1 - 1) ? spos + 1 : S1 - 1;
        int sposn = spos + sop;
        int bposn = bposc + bop;
        int ne    = (bposn > 0) ? 1 : 0;
        int gidx  = bposn - 1; if (gidx < 0) gidx = 0; if (gidx > SEQ - 1) gidx = SEQ - 1;
        ctl[3] = a; ctl[4] = push; ctl[5] = widx; ctl[6] = sposn;
        ctl[7] = bposn; ctl[8] = ne; ctl[9] = gidx;
      }
    }
    __syncthreads();

    // PHASE 5: gates + commit
    {
      const int a = ctl[3], push = ctl[4], widx = ctl[5];
      const int ne = ctl[8], gidx = ctl[9];
      if (tid < H){
        // stack LSTM gates (z = u1[0:1024])
        float zi = u1[tid], zf = u1[256+tid], zg = u1[512+tid], zo = u1[768+tid];
        float cold = scst[((size_t)b*S1 + spos)*H + tid];
        float c2 = sigf(zf)*cold + sigf(zi)*tanhf(zg);
        float h2 = sigf(zo)*tanhf(c2);
        if (push){
          stackh[widx*H + tid] = h2;
          scst[((size_t)b*S1 + widx)*H + tid] = c2;
        }
      } else if (tid < 2*H){
        // hist LSTM gates (zW = u1[1024:2048], + histxz[a])
        const int u = tid - H;
        const float* hx = histxz + (size_t)a*G4;
        float zi = u1[1024 +        u] + hx[       u];
        float zf = u1[1024 + 256 +  u] + hx[256 +  u];
        float zg = u1[1024 + 512 +  u] + hx[512 +  u];
        float zo = u1[1024 + 768 +  u] + hx[768 +  u];
        float c2 = sigf(zf)*acl[u] + sigf(zi)*tanhf(zg);
        float h2 = sigf(zo)*tanhf(c2);
        acl[u] = c2; ahl[u] = h2;
      } else if (tid < 3*H){
        const int j = tid - 2*H;
        bstate[j] = ne ? bufh[((size_t)b*SEQ + gidx)*H + j] : h0[j];
      }
      if (tid == 0){ ctl[0] = ctl[6]; ctl[1] = ctl[7]; ctl[2] = ctl[8] ? ctl[9] : SEQ; }
    }
    __syncthreads();
  }
}

extern "C" void kernel_launch(void* const* d_in, const int* in_sizes, int n_in,
                              void* d_out, int out_size, void* d_ws, size_t ws_size,
                              hipStream_t stream){
  (void)in_sizes; (void)n_in; (void)out_size; (void)ws_size;
  const int*   tokens    = (const int*)  d_in[0];
  const float* word_emb  = (const float*)d_in[1];
  const float* compose_W = (const float*)d_in[2];
  const float* compose_b = (const float*)d_in[3];
  const float* h0        = (const float*)d_in[4];
  const float* c0        = (const float*)d_in[5];
  const float* pb_Wih    = (const float*)d_in[6];
  const float* pb_Whh    = (const float*)d_in[7];
  const float* pb_bih    = (const float*)d_in[8];
  const float* pb_bhh    = (const float*)d_in[9];
  const float* st_Wih    = (const float*)d_in[10];
  const float* st_Whh    = (const float*)d_in[11];
  const float* st_bih    = (const float*)d_in[12];
  const float* st_bhh    = (const float*)d_in[13];
  const float* hist_Wih  = (const float*)d_in[14];
  const float* hist_Whh  = (const float*)d_in[15];
  const float* hist_bih  = (const float*)d_in[16];
  const float* hist_bhh  = (const float*)d_in[17];
  const float* sum_W     = (const float*)d_in[18];
  const float* sum_b     = (const float*)d_in[19];
  const float* act_W     = (const float*)d_in[20];
  const float* act_b     = (const float*)d_in[21];
  const float* action_emb= (const float*)d_in[22];
  const int*   stack_map = (const int*)  d_in[23];
  const int*   buffer_map= (const int*)  d_in[24];

  float* ws     = (float*)d_ws;
  float* pb_zx  = ws;                                  // 128*64*1024
  float* st_zx  = pb_zx + (size_t)NB*SEQ*G4;           // 128*65*1024
  float* bufh   = st_zx + (size_t)NB*(SEQ+1)*G4;       // 128*64*256
  float* scst   = bufh  + (size_t)NB*SEQ*H;            // 128*41*256
  float* histxz = scst  + (size_t)NB*S1*H;             // 64*1024
  float* Wt_pb  = histxz + (size_t)NA*G4;              // [256][1024]
  float* Wt_st  = Wt_pb  + (size_t)H*G4;
  float* Wt_hi  = Wt_st  + (size_t)H*G4;
  float* Wt_sum = Wt_hi  + (size_t)H*G4;               // [768][256]
  float* Wt_act = Wt_sum + (size_t)768*H;              // [256][64]
  float* Wt_pbih= Wt_act + (size_t)H*NA;               // [128][1024]
  float* Wt_stih= Wt_pbih+ (size_t)DIN*G4;             // [128][1024]
  float* Wt_cmp = Wt_stih+ (size_t)DIN*G4;             // [256][128]

  dim3 blk(32, 8);
  transpose_k<<<dim3(256/32, 1024/32), blk, 0, stream>>>(pb_Whh,   Wt_pb,  1024, 256);
  transpose_k<<<dim3(256/32, 1024/32), blk, 0, stream>>>(st_Whh,   Wt_st,  1024, 256);
  transpose_k<<<dim3(256/32, 1024/32), blk, 0, stream>>>(hist_Whh, Wt_hi,  1024, 256);
  transpose_k<<<dim3(768/32,  256/32), blk, 0, stream>>>(sum_W,    Wt_sum,  256, 768);
  transpose_k<<<dim3(256/32,   64/32), blk, 0, stream>>>(act_W,    Wt_act,   64, 256);
  transpose_k<<<dim3(128/32, 1024/32), blk, 0, stream>>>(pb_Wih,   Wt_pbih,1024, 128);
  transpose_k<<<dim3(128/32, 1024/32), blk, 0, stream>>>(st_Wih,   Wt_stih,1024, 128);
  transpose_k<<<dim3(256/32,  128/32), blk, 0, stream>>>(compose_W,Wt_cmp,  128, 256);
  hist_proj_kernel<<<dim3(NA), dim3(256), 0, stream>>>(hist_Wih, hist_bih, hist_bhh,
                                                       action_emb, histxz);

  parser_kernel<<<dim3(NB), dim3(1024), 0, stream>>>(tokens, word_emb, Wt_cmp, compose_b,
      h0, c0, Wt_pbih, Wt_pb, pb_bih, pb_bhh, Wt_stih, Wt_st, st_bih, st_bhh,
      Wt_hi, Wt_sum, sum_b, Wt_act, act_b, stack_map, buffer_map,
      histxz, pb_zx, st_zx, bufh, scst, (float*)d_out);
}